// Round 1
// baseline (115.810 us; speedup 1.0000x reference)
//
#include <hip/hip_runtime.h>

using f16x8 = _Float16 __attribute__((ext_vector_type(8)));
using f32x4 = float __attribute__((ext_vector_type(4)));

#define BS      8192
#define IN_DIM  4096
#define NB      64
#define BD      64
#define HID     256
#define OD      64
#define GY      16
#define ROWS_PER_WG (BS / GY)   // 512

__device__ __forceinline__ float gelu_f(float z) {
    // 0.5*z*(1+tanh(0.79788456*(z+0.044715*z^3))) rewritten as z*(1 - 1/(E+1)),
    // E = exp2(2.3021193*(z + 0.044715*z^3))
    float t = z * z;
    float p = __builtin_fmaf(0.044715f * z, t, z);
    float a = p * 2.3021193f;
    float e = __builtin_amdgcn_exp2f(a);
    float r = __builtin_amdgcn_rcpf(e + 1.0f);
    return __builtin_fmaf(-z, r, z);   // z*(1-r)
}

__global__ __launch_bounds__(256, 2) void blockmlp_kernel(
    const float* __restrict__ xg, const float* __restrict__ w1g,
    const float* __restrict__ b1g, const float* __restrict__ w2g,
    const float* __restrict__ b2g, float* __restrict__ outg) {

    __shared__ _Float16 W1T[HID * BD];   // [hidden o][k], XOR-swizzled, 32 KB
    __shared__ _Float16 Gs[4][1024];     // per-wave gelu scratch [32 r][32 kk], swizzled, 8 KB

    const int tid = threadIdx.x;
    const int w   = tid >> 6;
    const int l   = tid & 63;
    const int g   = l >> 4;      // lane group 0..3
    const int l15 = l & 15;
    const int n   = blockIdx.x;  // block index

    // ---- stage W1 -> LDS (transposed, f16, swizzled). W1[n] is [k=64][o=256].
    {
        const float* W1n = w1g + (size_t)n * (BD * HID);
        for (int it = 0; it < 64; ++it) {
            int e = tid + it * 256;      // coalesced over source
            int i = e >> 8;              // k
            int o = e & 255;             // hidden
            W1T[(o * 64 + i) ^ ((o & 7) << 3)] = (_Float16)W1n[e];
        }
    }

    // ---- gather all W2 B-fragments into registers (consistent k-map k = p*32+g*8+j)
    f16x8 b2r[8][4];
    {
        const float* W2n = w2g + (size_t)n * (HID * OD);
        #pragma unroll
        for (int p = 0; p < 8; ++p)
            #pragma unroll
            for (int n2 = 0; n2 < 4; ++n2) {
                f16x8 v;
                #pragma unroll
                for (int j = 0; j < 8; ++j)
                    v[j] = (_Float16)W2n[(p * 32 + g * 8 + j) * 64 + n2 * 16 + l15];
                b2r[p][n2] = v;
            }
    }

    // biases (b1,b2 are zeros in this problem but applied generically)
    float b1r[16];
    #pragma unroll
    for (int ht = 0; ht < 16; ++ht) b1r[ht] = b1g[n * HID + ht * 16 + l15];
    float b2b[4];
    #pragma unroll
    for (int n2 = 0; n2 < 4; ++n2) b2b[n2] = b2g[n * OD + n2 * 16 + l15];

    __syncthreads();   // W1T ready; only barrier in the kernel

    _Float16* gsw = &Gs[w][0];
    const f32x4 z4 = {0.0f, 0.0f, 0.0f, 0.0f};

    int row0 = blockIdx.y * ROWS_PER_WG + w * 32;
    for (int itr = 0; itr < ROWS_PER_WG / 128; ++itr, row0 += 128) {

        // ---- A1: load x fragment rows directly from global, cvt to f16
        f16x8 a1[2][2];
        #pragma unroll
        for (int msub = 0; msub < 2; ++msub)
            #pragma unroll
            for (int ks = 0; ks < 2; ++ks) {
                const float* px = xg + (size_t)(row0 + msub * 16 + l15) * IN_DIM
                                  + n * BD + ks * 32 + g * 8;
                float4 lo = *(const float4*)px;
                float4 hi = *(const float4*)(px + 4);
                f16x8 v;
                v[0] = (_Float16)lo.x; v[1] = (_Float16)lo.y;
                v[2] = (_Float16)lo.z; v[3] = (_Float16)lo.w;
                v[4] = (_Float16)hi.x; v[5] = (_Float16)hi.y;
                v[6] = (_Float16)hi.z; v[7] = (_Float16)hi.w;
                a1[msub][ks] = v;
            }

        f32x4 c2[2][4];
        #pragma unroll
        for (int msub = 0; msub < 2; ++msub)
            #pragma unroll
            for (int n2 = 0; n2 < 4; ++n2) c2[msub][n2] = z4;

        #pragma unroll
        for (int p = 0; p < 8; ++p) {
            // GEMM1 + bias + gelu for the two 16-wide hidden tiles of this pair
            #pragma unroll
            for (int htl = 0; htl < 2; ++htl) {
                const int ht = p * 2 + htl;
                const int o  = ht * 16 + l15;
                f32x4 c1a = z4, c1b = z4;
                #pragma unroll
                for (int ks = 0; ks < 2; ++ks) {
                    f16x8 bf = *(const f16x8*)&W1T[(o * 64 + ks * 32 + g * 8) ^ ((o & 7) << 3)];
                    c1a = __builtin_amdgcn_mfma_f32_16x16x32_f16(a1[0][ks], bf, c1a, 0, 0, 0);
                    c1b = __builtin_amdgcn_mfma_f32_16x16x32_f16(a1[1][ks], bf, c1b, 0, 0, 0);
                }
                // C layout (verified): col = l&15 (hidden), row = g*4 + q
                #pragma unroll
                for (int q = 0; q < 4; ++q) {
                    float z0 = c1a[q] + b1r[ht];
                    float z1 = c1b[q] + b1r[ht];
                    int kk = htl * 16 + l15;
                    int r0 = g * 4 + q;
                    int r1 = 16 + g * 4 + q;
                    gsw[(r0 * 32 + kk) ^ ((r0 & 7) << 3)] = (_Float16)gelu_f(z0);
                    gsw[(r1 * 32 + kk) ^ ((r1 & 7) << 3)] = (_Float16)gelu_f(z1);
                }
            }
            // GEMM2 partial: K-slice p*32..p*32+31 (same wave wrote Gs; compiler orders DS)
            #pragma unroll
            for (int msub = 0; msub < 2; ++msub) {
                int r = msub * 16 + l15;
                f16x8 a2 = *(const f16x8*)&gsw[(r * 32 + g * 8) ^ ((r & 7) << 3)];
                #pragma unroll
                for (int n2 = 0; n2 < 4; ++n2)
                    c2[msub][n2] = __builtin_amdgcn_mfma_f32_16x16x32_f16(a2, b2r[p][n2], c2[msub][n2], 0, 0, 0);
            }
        }

        // ---- epilogue: bias + store fp32
        #pragma unroll
        for (int msub = 0; msub < 2; ++msub)
            #pragma unroll
            for (int n2 = 0; n2 < 4; ++n2)
                #pragma unroll
                for (int q = 0; q < 4; ++q) {
                    int row = row0 + msub * 16 + g * 4 + q;
                    outg[(size_t)row * IN_DIM + n * BD + n2 * 16 + l15] = c2[msub][n2][q] + b2b[n2];
                }
    }
}

extern "C" void kernel_launch(void* const* d_in, const int* in_sizes, int n_in,
                              void* d_out, int out_size, void* d_ws, size_t ws_size,
                              hipStream_t stream) {
    const float* x  = (const float*)d_in[0];
    const float* W1 = (const float*)d_in[1];
    const float* b1 = (const float*)d_in[2];
    const float* W2 = (const float*)d_in[3];
    const float* b2 = (const float*)d_in[4];
    float* out = (float*)d_out;

    dim3 grid(NB, GY, 1);
    dim3 block(256, 1, 1);
    hipLaunchKernelGGL(blockmlp_kernel, grid, block, 0, stream, x, W1, b1, W2, b2, out);
}

// Round 2
// 78.463 us; speedup vs baseline: 1.4760x; 1.4760x over previous
//
#include <hip/hip_runtime.h>

using f16x8 = _Float16 __attribute__((ext_vector_type(8)));
using f32x4 = float __attribute__((ext_vector_type(4)));

#define BS      8192
#define IN_DIM  4096
#define NB      64
#define BD      64
#define HID     256
#define OD      64
#define GY      32

__device__ __forceinline__ float gelu_f(float z) {
    // tanh-form GELU via exp2: z * (1 - 1/(exp2(2.302119*(z+0.044715 z^3)) + 1))
    float t = z * z;
    float p = __builtin_fmaf(0.044715f * z, t, z);
    float e = __builtin_amdgcn_exp2f(p * 2.3021193f);
    float r = __builtin_amdgcn_rcpf(e + 1.0f);
    return __builtin_fmaf(-z, r, z);
}

__global__ __launch_bounds__(512, 4) void blockmlp_kernel(
    const float* __restrict__ xg, const float* __restrict__ w1g,
    const float* __restrict__ b1g, const float* __restrict__ w2g,
    const float* __restrict__ b2g, float* __restrict__ outg) {

    __shared__ _Float16 W1T[HID * BD];   // [o=256][k=64] f16, XOR-swizzled, 32 KB
    __shared__ _Float16 W2L[2048 * 8];   // B2 fragments, lane-linear, 32 KB
    __shared__ float    b1L[HID];        // 1 KB

    const int tid = threadIdx.x;
    const int w   = tid >> 6;
    const int l   = tid & 63;
    const int g   = l >> 4;
    const int l15 = l & 15;
    const int n   = blockIdx.x;

    // ---- stage W1 -> LDS transposed+swizzled. W1[n] is [k=64][o=256] row-major.
    const float* W1n = w1g + (size_t)n * (BD * HID);
    #pragma unroll
    for (int it = 0; it < 32; ++it) {
        int e = tid + it * 512;          // coalesced over source
        int i = e >> 8;                  // k
        int o = e & 255;                 // hidden
        W1T[(o * 64 + i) ^ ((o & 7) << 3)] = (_Float16)W1n[e];
    }

    // ---- stage W2 B-fragments (k-map k2(g,j) = (j>>2)*16 + g*4 + (j&3))
    const float* W2n = w2g + (size_t)n * (HID * OD);
    #pragma unroll
    for (int i4 = 0; i4 < 4; ++i4) {
        int e  = tid * 4 + i4;           // fragment-lane entry 0..2047
        int p  = e >> 8;
        int n2 = (e >> 6) & 3;
        int le = e & 63;
        int ge = le >> 4, ce = le & 15;
        f16x8 v;
        #pragma unroll
        for (int j = 0; j < 8; ++j)
            v[j] = (_Float16)W2n[(size_t)(p * 32 + ((j >> 2) << 4) + ge * 4 + (j & 3)) * 64 + n2 * 16 + ce];
        *(f16x8*)&W2L[e * 8] = v;
    }

    if (tid < HID) b1L[tid] = b1g[n * HID + tid];

    float b2b[4];
    #pragma unroll
    for (int n2 = 0; n2 < 4; ++n2) b2b[n2] = b2g[n * OD + n2 * 16 + l15];

    __syncthreads();   // only barrier

    const int row0 = blockIdx.y * 256 + w * 32;

    // ---- x fragments (B-operand of swapped GEMM1): lane: x[row0+rs*16+l15][k=ks*32+g*8+j]
    f16x8 xa[2][2];
    #pragma unroll
    for (int rs = 0; rs < 2; ++rs)
        #pragma unroll
        for (int ks = 0; ks < 2; ++ks) {
            const float* px = xg + (size_t)(row0 + rs * 16 + l15) * IN_DIM + n * BD + ks * 32 + g * 8;
            float4 lo = *(const float4*)px;
            float4 hi = *(const float4*)(px + 4);
            f16x8 v;
            v[0] = (_Float16)lo.x; v[1] = (_Float16)lo.y;
            v[2] = (_Float16)lo.z; v[3] = (_Float16)lo.w;
            v[4] = (_Float16)hi.x; v[5] = (_Float16)hi.y;
            v[6] = (_Float16)hi.z; v[7] = (_Float16)hi.w;
            xa[rs][ks] = v;
        }

    const f32x4 z4 = {0.0f, 0.0f, 0.0f, 0.0f};
    f32x4 c2[2][4];
    #pragma unroll
    for (int rs = 0; rs < 2; ++rs)
        #pragma unroll
        for (int n2 = 0; n2 < 4; ++n2) c2[rs][n2] = z4;

    const int swz = (l15 & 7) << 3;   // o&7 == l15&7 since tiles are 16-aligned

    #pragma unroll
    for (int p = 0; p < 8; ++p) {
        // GEMM1 (swapped): Sᵀ tiles for hidden ht=2p, 2p+1; lane gets S[row=l15][hid=ht*16+g*4+q]
        f32x4 c1[2][2];   // [htl][rs]
        #pragma unroll
        for (int htl = 0; htl < 2; ++htl) {
            const int o = (p * 2 + htl) * 16 + l15;
            f32x4 ca = z4, cb = z4;
            #pragma unroll
            for (int ks = 0; ks < 2; ++ks) {
                f16x8 wf = *(const f16x8*)&W1T[o * 64 + ((ks * 32 + g * 8) ^ swz)];
                ca = __builtin_amdgcn_mfma_f32_16x16x32_f16(wf, xa[0][ks], ca, 0, 0, 0);
                cb = __builtin_amdgcn_mfma_f32_16x16x32_f16(wf, xa[1][ks], cb, 0, 0, 0);
            }
            c1[htl][0] = ca; c1[htl][1] = cb;
        }
        // bias + gelu entirely in registers -> A2 fragments (k2-map by construction)
        f32x4 b1a = *(const f32x4*)&b1L[(p * 2 + 0) * 16 + g * 4];
        f32x4 b1b = *(const f32x4*)&b1L[(p * 2 + 1) * 16 + g * 4];
        f16x8 a2[2];
        #pragma unroll
        for (int rs = 0; rs < 2; ++rs) {
            f16x8 v;
            #pragma unroll
            for (int q = 0; q < 4; ++q) {
                v[q]     = (_Float16)gelu_f(c1[0][rs][q] + b1a[q]);
                v[q + 4] = (_Float16)gelu_f(c1[1][rs][q] + b1b[q]);
            }
            a2[rs] = v;
        }
        // GEMM2 partial: K-slice p*32..p*32+31
        #pragma unroll
        for (int n2 = 0; n2 < 4; ++n2) {
            f16x8 bf = *(const f16x8*)&W2L[((p * 4 + n2) * 64 + l) * 8];
            c2[0][n2] = __builtin_amdgcn_mfma_f32_16x16x32_f16(a2[0], bf, c2[0][n2], 0, 0, 0);
            c2[1][n2] = __builtin_amdgcn_mfma_f32_16x16x32_f16(a2[1], bf, c2[1][n2], 0, 0, 0);
        }
    }

    // ---- epilogue: bias + fp32 store
    #pragma unroll
    for (int rs = 0; rs < 2; ++rs)
        #pragma unroll
        for (int n2 = 0; n2 < 4; ++n2)
            #pragma unroll
            for (int q = 0; q < 4; ++q) {
                int row = row0 + rs * 16 + g * 4 + q;
                outg[(size_t)row * IN_DIM + n * BD + n2 * 16 + l15] = c2[rs][n2][q] + b2b[n2];
            }
}

extern "C" void kernel_launch(void* const* d_in, const int* in_sizes, int n_in,
                              void* d_out, int out_size, void* d_ws, size_t ws_size,
                              hipStream_t stream) {
    const float* x  = (const float*)d_in[0];
    const float* W1 = (const float*)d_in[1];
    const float* b1 = (const float*)d_in[2];
    const float* W2 = (const float*)d_in[3];
    const float* b2 = (const float*)d_in[4];
    float* out = (float*)d_out;

    dim3 grid(NB, GY, 1);
    dim3 block(512, 1, 1);
    hipLaunchKernelGGL(blockmlp_kernel, grid, block, 0, stream, x, W1, b1, W2, b2, out);
}